// Round 6
// baseline (132.207 us; speedup 1.0000x reference)
//
#include <hip/hip_runtime.h>

#define NB    8
#define CIN   128
#define COUT  128
#define HH    32
#define WW    32
#define HO    34
#define WO    34
#define SSP   (HO*WO)     // 1156
#define SPAD  1160        // padded pixel count
#define UU    6
#define NS    (SPAD*UU)   // 6960 = 145*48, N per (b,c)
#define NT    48          // GEMM N-tile = 8 pixels x 6 u
#define EPSC  1e-7f

typedef __attribute__((ext_vector_type(8))) short bf16x8;
typedef __attribute__((ext_vector_type(4))) float f32x4;

__device__ __forceinline__ ushort f2b(float f) {
  uint u = __float_as_uint(f);
  uint r = (u + 0x7fffu + ((u >> 16) & 1u)) >> 16;
  return (ushort)r;
}

// ---- prep: M2[tap][u][9] combined symmetric operators + wT[o][c]=bf16(g^2) ----
__global__ void prep_kernel(const float* __restrict__ g,
                            float* __restrict__ M2,
                            ushort* __restrict__ wT) {
  if (blockIdx.x == 0) {
    __shared__ float Gs[81];
    int t = threadIdx.x;
    if (t < 9) {
      const int nums[9] = {0,1,2,3,0,5,6,7,1};
      float a = g[2*nums[t]];
      float c = g[2*nums[t]+1];
      float F[9], S2[9];
      if (t == 4) {
        F[0]=1;F[1]=0;F[2]=0;F[3]=0;F[4]=1;F[5]=0;F[6]=0;F[7]=0;F[8]=1;
        S2[0]=1;S2[1]=0;S2[2]=0;S2[3]=0;S2[4]=1;S2[5]=0;S2[6]=0;S2[7]=0;S2[8]=1;
      } else {
        F[0]=1.f; F[1]=-a;  F[2]=-a;
        F[3]=a;   F[4]=1.f; F[5]=-c;
        F[6]=a;   F[7]=c;   F[8]=1.f;
        S2[0]=1.f;  S2[1]=a;   S2[2]=a;
        S2[3]=-a;   S2[4]=1.f; S2[5]=c;
        S2[6]=-a;   S2[7]=-c;  S2[8]=1.f;
      }
      float det = F[0]*(F[4]*F[8]-F[5]*F[7]) - F[1]*(F[3]*F[8]-F[5]*F[6])
                + F[2]*(F[3]*F[7]-F[4]*F[6]) + EPSC;
      float inv[9];
      inv[0] = (F[4]*F[8]-F[5]*F[7]);
      inv[1] = (F[2]*F[7]-F[1]*F[8]);
      inv[2] = (F[1]*F[5]-F[2]*F[4]);
      inv[3] = (F[5]*F[6]-F[3]*F[8]);
      inv[4] = (F[0]*F[8]-F[2]*F[6]);
      inv[5] = (F[2]*F[3]-F[0]*F[5]);
      inv[6] = (F[3]*F[7]-F[4]*F[6]);
      inv[7] = (F[1]*F[6]-F[0]*F[7]);
      inv[8] = (F[0]*F[4]-F[1]*F[3]);
      float rd = 1.0f/det;
      #pragma unroll
      for (int i = 0; i < 9; ++i) inv[i] *= rd;
      #pragma unroll
      for (int i = 0; i < 3; ++i)
        #pragma unroll
        for (int j = 0; j < 3; ++j)
          Gs[t*9+i*3+j] = inv[i*3+0]*S2[0*3+j] + inv[i*3+1]*S2[1*3+j] + inv[i*3+2]*S2[2*3+j];
    }
    __syncthreads();
    if (t < 6) {
      const int T1[6] = {0,1,2,4,5,8};
      const int T2[6] = {0,3,6,4,7,8};
      int t1 = T1[t], t2 = T2[t];
      for (int co = 0; co < 9; ++co) {       // co = tap = i*3+j
        int i = co/3, j = co%3;
        for (int k = 0; k < 9; ++k) {
          int p = k/3, q = k%3;
          M2[(co*6 + t)*9 + k] =
            0.5f*(Gs[t1*9+i*3+p]*Gs[t1*9+j*3+q] + Gs[t2*9+i*3+p]*Gs[t2*9+j*3+q]);
        }
      }
    }
  } else {
    int idx = (int)(blockIdx.x-1)*256 + threadIdx.x;   // idx = o*128 + c
    int o = idx >> 7, c = idx & 127;
    float w = g[16 + c*128 + o];
    wT[idx] = f2b(w*w);
  }
}

// ---- fold: direct gather; coefficient loads ping-pong-pipelined across taps ----
// folded_u(s) = sum_{tap=(i,j)} M2[tap][u] . x[s-(i,j)]  (invalid taps -> zero slot)
__global__ __launch_bounds__(512) void fold_kernel(const float* __restrict__ x,
                                                   const float* __restrict__ M2,
                                                   ushort* __restrict__ folded) {
  __shared__ float4 XsA[1025];   // x[px][0..3]; px 1024 = zero slot
  __shared__ float4 XsB[1025];   // x[px][4..7]
  __shared__ float  XsC[1025];   // x[px][8]     total ~36.9 KB
  int tid = threadIdx.x;
  const float* xb = x + (size_t)blockIdx.x * (HH*WW*9);

  #pragma unroll
  for (int kk = 0; kk < 2; ++kk) {
    int px = tid + kk*512;
    const float* p = xb + px*9;
    XsA[px] = make_float4(p[0],p[1],p[2],p[3]);
    XsB[px] = make_float4(p[4],p[5],p[6],p[7]);
    XsC[px] = p[8];
  }
  if (tid == 0) {
    XsA[1024] = make_float4(0.f,0.f,0.f,0.f);
    XsB[1024] = make_float4(0.f,0.f,0.f,0.f);
    XsC[1024] = 0.f;
  }
  __syncthreads();

  float acc[3][6];
  #pragma unroll
  for (int r = 0; r < 3; ++r)
    #pragma unroll
    for (int u = 0; u < 6; ++u) acc[r][u] = 0.f;

  int hoA[3], woA[3];
  #pragma unroll
  for (int r = 0; r < 3; ++r) {
    int idx = tid + r*512;
    int hh = (int)((uint)idx / 34u);
    hoA[r] = hh;
    woA[r] = idx - 34*hh;
  }

  float ca[27], cb[27];
  #pragma unroll
  for (int j = 0; j < 27; ++j) ca[j] = M2[j];     // tap0 chunk0 (u=0..2)

  int ti = 0, tj = 0;
  for (int tap = 0; tap < 9; ++tap) {
    const float* base = M2 + tap*54;
    #pragma unroll
    for (int j = 0; j < 27; ++j) cb[j] = base[27 + j];   // current tap chunk1 (u=3..5)

    float v[3][9];
    #pragma unroll
    for (int r = 0; r < 3; ++r) {
      int idx = tid + r*512;
      int hh = hoA[r] - ti;
      int wj = woA[r] - tj;
      bool ok = ((uint)hh < 32u) && ((uint)wj < 32u) && (r < 2 || idx < SSP);
      int px = ok ? (hh*32 + wj) : 1024;
      float4 a = XsA[px];
      float4 b = XsB[px];
      float  c = XsC[px];
      v[r][0]=a.x; v[r][1]=a.y; v[r][2]=a.z; v[r][3]=a.w;
      v[r][4]=b.x; v[r][5]=b.y; v[r][6]=b.z; v[r][7]=b.w;
      v[r][8]=c;
      #pragma unroll
      for (int u = 0; u < 3; ++u) {
        float d = ca[u*9]*v[r][0];
        #pragma unroll
        for (int k = 1; k < 9; ++k) d = fmaf(ca[u*9+k], v[r][k], d);
        acc[r][u] += d;
      }
    }

    const float* basen = M2 + ((tap < 8) ? (tap+1)*54 : 8*54);
    #pragma unroll
    for (int j = 0; j < 27; ++j) ca[j] = basen[j];       // next tap chunk0

    #pragma unroll
    for (int r = 0; r < 3; ++r) {
      #pragma unroll
      for (int u = 0; u < 3; ++u) {
        float d = cb[u*9]*v[r][0];
        #pragma unroll
        for (int k = 1; k < 9; ++k) d = fmaf(cb[u*9+k], v[r][k], d);
        acc[r][3+u] += d;
      }
    }

    if (++tj == 3) { tj = 0; ++ti; }
  }

  // pack 6 bf16 -> 3 dwords per pixel; zeros fill the pad region [1156,1160)
  uint* outp = (uint*)folded + (size_t)blockIdx.x * (NS/2);
  #pragma unroll
  for (int r = 0; r < 3; ++r) {
    int idx = tid + r*512;
    if (idx < SPAD) {
      uint p0 = (uint)f2b(acc[r][0]) | ((uint)f2b(acc[r][1]) << 16);
      uint p1 = (uint)f2b(acc[r][2]) | ((uint)f2b(acc[r][3]) << 16);
      uint p2 = (uint)f2b(acc[r][4]) | ((uint)f2b(acc[r][5]) << 16);
      outp[idx*3+0] = p0;
      outp[idx*3+1] = p1;
      outp[idx*3+2] = p2;
    }
  }
}

// ---- gemm: C[o][n] = sum_c wT[o][c]*folded[b][c][n]; n = s*6+u ----
// N-tile = 48 = 8 pixels x 6 u -> epilogue assembles full 36B pixels, coalesced.
__global__ __launch_bounds__(192) void gemm_kernel(const ushort* __restrict__ wT,
                                                   const ushort* __restrict__ folded,
                                                   float* __restrict__ out) {
  __shared__ __align__(16) char smem[128*52*4];   // 26,624 B (ldsB and ldsC alias)
  ushort* ldsB = (ushort*)smem;                   // [48][136] swizzled
  float*  ldsC = (float*)smem;                    // [128][52]

  int tid  = threadIdx.x;
  int b    = blockIdx.y;
  int tile = blockIdx.x;
  int n0   = tile * NT;

  // stage B panel [48 n][128 k], transpose + XOR swizzle
  #pragma unroll
  for (int p = 0; p < 4; ++p) {
    int chunk = tid + p*192;              // 0..767 ; c = chunk/6, nc = (chunk%6)*8
    int c  = chunk / 6;
    int nc = (chunk - 6*c) * 8;
    const ushort* src = folded + ((size_t)(b*CIN + c)*NS + n0 + nc);
    uint4 v = *(const uint4*)src;
    ushort e[8];
    e[0]=(ushort)(v.x & 0xffffu); e[1]=(ushort)(v.x >> 16);
    e[2]=(ushort)(v.y & 0xffffu); e[3]=(ushort)(v.y >> 16);
    e[4]=(ushort)(v.z & 0xffffu); e[5]=(ushort)(v.z >> 16);
    e[6]=(ushort)(v.w & 0xffffu); e[7]=(ushort)(v.w >> 16);
    #pragma unroll
    for (int j = 0; j < 8; ++j) {
      int nl  = nc + j;
      int ksw = c ^ (((nl >> 3) & 7) << 4);
      ldsB[nl*136 + ksw] = e[j];
    }
  }
  __syncthreads();

  int wave = tid >> 6, lane = tid & 63;
  int l15 = lane & 15, lhi = lane >> 4;
  int nl = wave*16 + l15;                 // 0..47
  int sw = ((nl >> 3) & 7) << 4;

  f32x4 acc[8];
  #pragma unroll
  for (int i = 0; i < 8; ++i) acc[i] = (f32x4){0.f,0.f,0.f,0.f};

  const ushort* wrow = wT + l15*128;
  #pragma unroll
  for (int k0 = 0; k0 < 128; k0 += 32) {
    int kk = k0 + lhi*8;
    bf16x8 bfrag = *(const bf16x8*)&ldsB[nl*136 + (kk ^ sw)];
    #pragma unroll
    for (int mf = 0; mf < 8; ++mf) {
      bf16x8 afrag = *(const bf16x8*)(wrow + mf*16*128 + kk);
      acc[mf] = __builtin_amdgcn_mfma_f32_16x16x32_bf16(afrag, bfrag, acc[mf], 0, 0, 0);
    }
  }

  __syncthreads();   // done reading ldsB
  #pragma unroll
  for (int mf = 0; mf < 8; ++mf)
    #pragma unroll
    for (int r = 0; r < 4; ++r) {
      int o = mf*16 + lhi*4 + r;
      ldsC[o*52 + nl] = acc[mf][r];       // 2-way bank alias only
    }
  __syncthreads();

  // write: one (o, s) pixel per thread-iter -> 9 contiguous f32 (36 B)
  int s0 = tile * 8;
  const int umap[9] = {0,1,2,1,3,4,2,4,5};
  #pragma unroll
  for (int r = 0; r < 6; ++r) {
    int pair = tid + r*192;
    if (pair < 1024) {
      int o  = pair >> 3;
      int sl = pair & 7;
      int s  = s0 + sl;
      if (s < SSP) {
        float v[6];
        #pragma unroll
        for (int u = 0; u < 6; ++u) v[u] = ldsC[o*52 + sl*6 + u];
        size_t base = ((size_t)(b*COUT + o)*SSP + s)*9;
        #pragma unroll
        for (int t = 0; t < 9; ++t) out[base + t] = v[umap[t]];
      }
    }
  }
}

extern "C" void kernel_launch(void* const* d_in, const int* in_sizes, int n_in,
                              void* d_out, int out_size, void* d_ws, size_t ws_size,
                              hipStream_t stream) {
  const float* x = (const float*)d_in[0];
  const float* g = (const float*)d_in[1];
  float* out = (float*)d_out;

  float*  M2     = (float*)d_ws;                          // 486 f32 = 1944 B
  ushort* wT     = (ushort*)((char*)d_ws + 4096);         // 128*128 bf16 = 32 KB
  ushort* folded = (ushort*)((char*)d_ws + 4096 + 32768); // 8*128*6960 bf16 = 14.25 MB

  prep_kernel<<<65, 256, 0, stream>>>(g, M2, wT);
  fold_kernel<<<NB*CIN, 512, 0, stream>>>(x, M2, folded);
  gemm_kernel<<<dim3(NS/NT, NB), 192, 0, stream>>>(wT, folded, out);
}

// Round 7
// 130.697 us; speedup vs baseline: 1.0116x; 1.0116x over previous
//
#include <hip/hip_runtime.h>

#define NB    8
#define CIN   128
#define COUT  128
#define HH    32
#define WW    32
#define HO    34
#define WO    34
#define SSP   (HO*WO)     // 1156
#define SPAD  1160        // padded pixel count
#define UU    6
#define NS    (SPAD*UU)   // 6960 = 145*48, N per (b,c)
#define NT    48          // GEMM N-tile = 8 pixels x 6 u
#define EPSC  1e-7f

typedef __attribute__((ext_vector_type(8))) short bf16x8;
typedef __attribute__((ext_vector_type(4))) float f32x4;
typedef __attribute__((ext_vector_type(2))) float f32x2;

__device__ __forceinline__ ushort f2b(float f) {
  uint u = __float_as_uint(f);
  uint r = (u + 0x7fffu + ((u >> 16) & 1u)) >> 16;
  return (ushort)r;
}

// ---- prep: M3[tap][k][u] (u innermost -> f32x2 pairs) + wT[o][c]=bf16(g^2) ----
__global__ void prep_kernel(const float* __restrict__ g,
                            float* __restrict__ M3,
                            ushort* __restrict__ wT) {
  if (blockIdx.x == 0) {
    __shared__ float Gs[81];
    int t = threadIdx.x;
    if (t < 9) {
      const int nums[9] = {0,1,2,3,0,5,6,7,1};
      float a = g[2*nums[t]];
      float c = g[2*nums[t]+1];
      float F[9], S2[9];
      if (t == 4) {
        F[0]=1;F[1]=0;F[2]=0;F[3]=0;F[4]=1;F[5]=0;F[6]=0;F[7]=0;F[8]=1;
        S2[0]=1;S2[1]=0;S2[2]=0;S2[3]=0;S2[4]=1;S2[5]=0;S2[6]=0;S2[7]=0;S2[8]=1;
      } else {
        F[0]=1.f; F[1]=-a;  F[2]=-a;
        F[3]=a;   F[4]=1.f; F[5]=-c;
        F[6]=a;   F[7]=c;   F[8]=1.f;
        S2[0]=1.f;  S2[1]=a;   S2[2]=a;
        S2[3]=-a;   S2[4]=1.f; S2[5]=c;
        S2[6]=-a;   S2[7]=-c;  S2[8]=1.f;
      }
      float det = F[0]*(F[4]*F[8]-F[5]*F[7]) - F[1]*(F[3]*F[8]-F[5]*F[6])
                + F[2]*(F[3]*F[7]-F[4]*F[6]) + EPSC;
      float inv[9];
      inv[0] = (F[4]*F[8]-F[5]*F[7]);
      inv[1] = (F[2]*F[7]-F[1]*F[8]);
      inv[2] = (F[1]*F[5]-F[2]*F[4]);
      inv[3] = (F[5]*F[6]-F[3]*F[8]);
      inv[4] = (F[0]*F[8]-F[2]*F[6]);
      inv[5] = (F[2]*F[3]-F[0]*F[5]);
      inv[6] = (F[3]*F[7]-F[4]*F[6]);
      inv[7] = (F[1]*F[6]-F[0]*F[7]);
      inv[8] = (F[0]*F[4]-F[1]*F[3]);
      float rd = 1.0f/det;
      #pragma unroll
      for (int i = 0; i < 9; ++i) inv[i] *= rd;
      #pragma unroll
      for (int i = 0; i < 3; ++i)
        #pragma unroll
        for (int j = 0; j < 3; ++j)
          Gs[t*9+i*3+j] = inv[i*3+0]*S2[0*3+j] + inv[i*3+1]*S2[1*3+j] + inv[i*3+2]*S2[2*3+j];
    }
    __syncthreads();
    if (t < 6) {
      const int T1[6] = {0,1,2,4,5,8};
      const int T2[6] = {0,3,6,4,7,8};
      int t1 = T1[t], t2 = T2[t];
      for (int co = 0; co < 9; ++co) {       // co = tap = i*3+j
        int i = co/3, j = co%3;
        for (int k = 0; k < 9; ++k) {
          int p = k/3, q = k%3;
          M3[(co*9 + k)*6 + t] =
            0.5f*(Gs[t1*9+i*3+p]*Gs[t1*9+j*3+q] + Gs[t2*9+i*3+p]*Gs[t2*9+j*3+q]);
        }
      }
    }
  } else {
    int idx = (int)(blockIdx.x-1)*256 + threadIdx.x;   // idx = o*128 + c
    int o = idx >> 7, c = idx & 127;
    float w = g[16 + c*128 + o];
    wT[idx] = f2b(w*w);
  }
}

// ---- fold: direct gather; u-paired packed FMA (v_pk_fma_f32) dots ----
// folded_u(s) = sum_{tap=(i,j)} M3[tap][.][u] . x[s-(i,j)]  (invalid taps -> zero slot)
__global__ __launch_bounds__(512, 6) void fold_kernel(const float* __restrict__ x,
                                                      const float* __restrict__ M3,
                                                      ushort* __restrict__ folded) {
  __shared__ float4 XsA[1025];   // x[px][0..3]; px 1024 = zero slot
  __shared__ float4 XsB[1025];   // x[px][4..7]
  __shared__ float  XsC[1025];   // x[px][8]     total ~36.9 KB
  int tid = threadIdx.x;
  const float* xb = x + (size_t)blockIdx.x * (HH*WW*9);

  #pragma unroll
  for (int kk = 0; kk < 2; ++kk) {
    int px = tid + kk*512;
    const float* p = xb + px*9;
    XsA[px] = make_float4(p[0],p[1],p[2],p[3]);
    XsB[px] = make_float4(p[4],p[5],p[6],p[7]);
    XsC[px] = p[8];
  }
  if (tid == 0) {
    XsA[1024] = make_float4(0.f,0.f,0.f,0.f);
    XsB[1024] = make_float4(0.f,0.f,0.f,0.f);
    XsC[1024] = 0.f;
  }
  __syncthreads();

  f32x2 acc2[3][3];              // [pixel r][u-pair j] ; u = j*2 + lane-of-pair
  #pragma unroll
  for (int r = 0; r < 3; ++r)
    #pragma unroll
    for (int j = 0; j < 3; ++j) acc2[r][j] = (f32x2){0.f, 0.f};

  int hoA[3], woA[3];
  #pragma unroll
  for (int r = 0; r < 3; ++r) {
    int idx = tid + r*512;
    int hh = (int)((uint)idx / 34u);
    hoA[r] = hh;
    woA[r] = idx - 34*hh;
  }

  int ti = 0, tj = 0;
  for (int tap = 0; tap < 9; ++tap) {
    // 27 coefficient pairs for this tap: uniform address -> s_load, SGPR pairs
    const f32x2* C2 = (const f32x2*)(M3 + tap*54);
    f32x2 c[27];
    #pragma unroll
    for (int j = 0; j < 27; ++j) c[j] = C2[j];

    #pragma unroll
    for (int r = 0; r < 3; ++r) {
      int idx = tid + r*512;
      int hh = hoA[r] - ti;
      int wj = woA[r] - tj;
      bool ok = ((uint)hh < 32u) && ((uint)wj < 32u) && (r < 2 || idx < SSP);
      int px = ok ? (hh*32 + wj) : 1024;
      float4 a = XsA[px];
      float4 b = XsB[px];
      float  cc = XsC[px];
      float v[9] = {a.x,a.y,a.z,a.w,b.x,b.y,b.z,b.w,cc};
      #pragma unroll
      for (int k = 0; k < 9; ++k) {
        f32x2 vk = (f32x2){v[k], v[k]};
        acc2[r][0] = __builtin_elementwise_fma(c[k*3+0], vk, acc2[r][0]);
        acc2[r][1] = __builtin_elementwise_fma(c[k*3+1], vk, acc2[r][1]);
        acc2[r][2] = __builtin_elementwise_fma(c[k*3+2], vk, acc2[r][2]);
      }
    }

    if (++tj == 3) { tj = 0; ++ti; }
  }

  // pack 6 bf16 -> 3 dwords per pixel; zeros fill the pad region [1156,1160)
  uint* outp = (uint*)folded + (size_t)blockIdx.x * (NS/2);
  #pragma unroll
  for (int r = 0; r < 3; ++r) {
    int idx = tid + r*512;
    if (idx < SPAD) {
      uint p0 = (uint)f2b(acc2[r][0].x) | ((uint)f2b(acc2[r][0].y) << 16);
      uint p1 = (uint)f2b(acc2[r][1].x) | ((uint)f2b(acc2[r][1].y) << 16);
      uint p2 = (uint)f2b(acc2[r][2].x) | ((uint)f2b(acc2[r][2].y) << 16);
      outp[idx*3+0] = p0;
      outp[idx*3+1] = p1;
      outp[idx*3+2] = p2;
    }
  }
}

// ---- gemm: C[o][n] = sum_c wT[o][c]*folded[b][c][n]; n = s*6+u ----
// N-tile = 48 = 8 pixels x 6 u -> epilogue assembles full 36B pixels, coalesced.
__global__ __launch_bounds__(192) void gemm_kernel(const ushort* __restrict__ wT,
                                                   const ushort* __restrict__ folded,
                                                   float* __restrict__ out) {
  __shared__ __align__(16) char smem[128*52*4];   // 26,624 B (ldsB and ldsC alias)
  ushort* ldsB = (ushort*)smem;                   // [48][136] swizzled
  float*  ldsC = (float*)smem;                    // [128][52]

  int tid  = threadIdx.x;
  int b    = blockIdx.y;
  int tile = blockIdx.x;
  int n0   = tile * NT;

  // stage B panel [48 n][128 k], transpose + XOR swizzle
  #pragma unroll
  for (int p = 0; p < 4; ++p) {
    int chunk = tid + p*192;              // 0..767 ; c = chunk/6, nc = (chunk%6)*8
    int c  = chunk / 6;
    int nc = (chunk - 6*c) * 8;
    const ushort* src = folded + ((size_t)(b*CIN + c)*NS + n0 + nc);
    uint4 v = *(const uint4*)src;
    ushort e[8];
    e[0]=(ushort)(v.x & 0xffffu); e[1]=(ushort)(v.x >> 16);
    e[2]=(ushort)(v.y & 0xffffu); e[3]=(ushort)(v.y >> 16);
    e[4]=(ushort)(v.z & 0xffffu); e[5]=(ushort)(v.z >> 16);
    e[6]=(ushort)(v.w & 0xffffu); e[7]=(ushort)(v.w >> 16);
    #pragma unroll
    for (int j = 0; j < 8; ++j) {
      int nl  = nc + j;
      int ksw = c ^ (((nl >> 3) & 7) << 4);
      ldsB[nl*136 + ksw] = e[j];
    }
  }
  __syncthreads();

  int wave = tid >> 6, lane = tid & 63;
  int l15 = lane & 15, lhi = lane >> 4;
  int nl = wave*16 + l15;                 // 0..47
  int sw = ((nl >> 3) & 7) << 4;

  f32x4 acc[8];
  #pragma unroll
  for (int i = 0; i < 8; ++i) acc[i] = (f32x4){0.f,0.f,0.f,0.f};

  const ushort* wrow = wT + l15*128;
  #pragma unroll
  for (int k0 = 0; k0 < 128; k0 += 32) {
    int kk = k0 + lhi*8;
    bf16x8 bfrag = *(const bf16x8*)&ldsB[nl*136 + (kk ^ sw)];
    #pragma unroll
    for (int mf = 0; mf < 8; ++mf) {
      bf16x8 afrag = *(const bf16x8*)(wrow + mf*16*128 + kk);
      acc[mf] = __builtin_amdgcn_mfma_f32_16x16x32_bf16(afrag, bfrag, acc[mf], 0, 0, 0);
    }
  }

  __syncthreads();   // done reading ldsB
  #pragma unroll
  for (int mf = 0; mf < 8; ++mf)
    #pragma unroll
    for (int r = 0; r < 4; ++r) {
      int o = mf*16 + lhi*4 + r;
      ldsC[o*52 + nl] = acc[mf][r];       // 2-way bank alias only
    }
  __syncthreads();

  // write: one (o, s) pixel per thread-iter -> 9 contiguous f32 (36 B)
  int s0 = tile * 8;
  const int umap[9] = {0,1,2,1,3,4,2,4,5};
  #pragma unroll
  for (int r = 0; r < 6; ++r) {
    int pair = tid + r*192;
    if (pair < 1024) {
      int o  = pair >> 3;
      int sl = pair & 7;
      int s  = s0 + sl;
      if (s < SSP) {
        float v[6];
        #pragma unroll
        for (int u = 0; u < 6; ++u) v[u] = ldsC[o*52 + sl*6 + u];
        size_t base = ((size_t)(b*COUT + o)*SSP + s)*9;
        #pragma unroll
        for (int t = 0; t < 9; ++t) out[base + t] = v[umap[t]];
      }
    }
  }
}

extern "C" void kernel_launch(void* const* d_in, const int* in_sizes, int n_in,
                              void* d_out, int out_size, void* d_ws, size_t ws_size,
                              hipStream_t stream) {
  const float* x = (const float*)d_in[0];
  const float* g = (const float*)d_in[1];
  float* out = (float*)d_out;

  float*  M3     = (float*)d_ws;                          // 486 f32 = 1944 B
  ushort* wT     = (ushort*)((char*)d_ws + 4096);         // 128*128 bf16 = 32 KB
  ushort* folded = (ushort*)((char*)d_ws + 4096 + 32768); // 8*128*6960 bf16 = 14.25 MB

  prep_kernel<<<65, 256, 0, stream>>>(g, M3, wT);
  fold_kernel<<<NB*CIN, 512, 0, stream>>>(x, M3, folded);
  gemm_kernel<<<dim3(NS/NT, NB), 192, 0, stream>>>(wT, folded, out);
}

// Round 8
// 128.993 us; speedup vs baseline: 1.0249x; 1.0132x over previous
//
#include <hip/hip_runtime.h>

#define NB    8
#define CIN   128
#define COUT  128
#define HH    32
#define WW    32
#define HO    34
#define WO    34
#define SSP   (HO*WO)     // 1156
#define SPAD  1160        // padded pixel count
#define UU    6
#define NS    (SPAD*UU)   // 6960 = 145*48, N per (b,c)
#define NT    48          // GEMM N-tile = 8 pixels x 6 u
#define EPSC  1e-7f

typedef __attribute__((ext_vector_type(8))) short bf16x8;
typedef __attribute__((ext_vector_type(4))) float f32x4;
typedef __attribute__((ext_vector_type(2))) _Float16 h2;

__device__ __forceinline__ ushort f2b(float f) {
  uint u = __float_as_uint(f);
  uint r = (u + 0x7fffu + ((u >> 16) & 1u)) >> 16;
  return (ushort)r;
}
__device__ __forceinline__ uint pkh(float a, float b) {
  return __builtin_bit_cast(uint, __builtin_amdgcn_cvt_pkrtz(a, b));
}
__device__ __forceinline__ h2 ash2(uint u) { return __builtin_bit_cast(h2, u); }

// ---- prep: Mh[tap][u][5] f16x2-packed operators + wT[o][c]=bf16(g^2) ----
__global__ void prep_kernel(const float* __restrict__ g,
                            uint* __restrict__ Mh,
                            ushort* __restrict__ wT) {
  if (blockIdx.x == 0) {
    __shared__ float Gs[81];
    int t = threadIdx.x;
    if (t < 9) {
      const int nums[9] = {0,1,2,3,0,5,6,7,1};
      float a = g[2*nums[t]];
      float c = g[2*nums[t]+1];
      float F[9], S2[9];
      if (t == 4) {
        F[0]=1;F[1]=0;F[2]=0;F[3]=0;F[4]=1;F[5]=0;F[6]=0;F[7]=0;F[8]=1;
        S2[0]=1;S2[1]=0;S2[2]=0;S2[3]=0;S2[4]=1;S2[5]=0;S2[6]=0;S2[7]=0;S2[8]=1;
      } else {
        F[0]=1.f; F[1]=-a;  F[2]=-a;
        F[3]=a;   F[4]=1.f; F[5]=-c;
        F[6]=a;   F[7]=c;   F[8]=1.f;
        S2[0]=1.f;  S2[1]=a;   S2[2]=a;
        S2[3]=-a;   S2[4]=1.f; S2[5]=c;
        S2[6]=-a;   S2[7]=-c;  S2[8]=1.f;
      }
      float det = F[0]*(F[4]*F[8]-F[5]*F[7]) - F[1]*(F[3]*F[8]-F[5]*F[6])
                + F[2]*(F[3]*F[7]-F[4]*F[6]) + EPSC;
      float inv[9];
      inv[0] = (F[4]*F[8]-F[5]*F[7]);
      inv[1] = (F[2]*F[7]-F[1]*F[8]);
      inv[2] = (F[1]*F[5]-F[2]*F[4]);
      inv[3] = (F[5]*F[6]-F[3]*F[8]);
      inv[4] = (F[0]*F[8]-F[2]*F[6]);
      inv[5] = (F[2]*F[3]-F[0]*F[5]);
      inv[6] = (F[3]*F[7]-F[4]*F[6]);
      inv[7] = (F[1]*F[6]-F[0]*F[7]);
      inv[8] = (F[0]*F[4]-F[1]*F[3]);
      float rd = 1.0f/det;
      #pragma unroll
      for (int i = 0; i < 9; ++i) inv[i] *= rd;
      #pragma unroll
      for (int i = 0; i < 3; ++i)
        #pragma unroll
        for (int j = 0; j < 3; ++j)
          Gs[t*9+i*3+j] = inv[i*3+0]*S2[0*3+j] + inv[i*3+1]*S2[1*3+j] + inv[i*3+2]*S2[2*3+j];
    }
    __syncthreads();
    if (t < 6) {
      const int T1[6] = {0,1,2,4,5,8};
      const int T2[6] = {0,3,6,4,7,8};
      int t1 = T1[t], t2 = T2[t];
      for (int tap = 0; tap < 9; ++tap) {
        int i = tap/3, j = tap%3;
        float m[10];
        for (int k = 0; k < 9; ++k) {
          int p = k/3, q = k%3;
          m[k] = 0.5f*(Gs[t1*9+i*3+p]*Gs[t1*9+j*3+q] + Gs[t2*9+i*3+p]*Gs[t2*9+j*3+q]);
        }
        m[9] = 0.f;
        for (int d = 0; d < 5; ++d)
          Mh[(tap*6 + t)*5 + d] = pkh(m[2*d], m[2*d+1]);
      }
    }
  } else {
    int idx = (int)(blockIdx.x-1)*256 + threadIdx.x;   // idx = o*128 + c
    int o = idx >> 7, c = idx & 127;
    float w = g[16 + c*128 + o];
    wT[idx] = f2b(w*w);
  }
}

// ---- fold: direct gather; f16 dot2 (2x f32 FMA rate), x packed f16 in LDS ----
__global__ __launch_bounds__(512, 6) void fold_kernel(const float* __restrict__ x,
                                                      const uint* __restrict__ Mh,
                                                      ushort* __restrict__ folded) {
  __shared__ uint2 XsA[1025];   // f16: x0x1, x2x3 ; px 1024 = zero slot
  __shared__ uint2 XsB[1025];   // f16: x4x5, x6x7
  __shared__ uint  XsC[1025];   // f16: x8, 0        total ~20.5 KB
  int tid = threadIdx.x;
  const float* xb = x + (size_t)blockIdx.x * (HH*WW*9);

  #pragma unroll
  for (int kk = 0; kk < 2; ++kk) {
    int px = tid + kk*512;
    const float* p = xb + px*9;
    XsA[px] = make_uint2(pkh(p[0],p[1]), pkh(p[2],p[3]));
    XsB[px] = make_uint2(pkh(p[4],p[5]), pkh(p[6],p[7]));
    XsC[px] = pkh(p[8], 0.f);
  }
  if (tid == 0) {
    XsA[1024] = make_uint2(0u,0u);
    XsB[1024] = make_uint2(0u,0u);
    XsC[1024] = 0u;
  }
  __syncthreads();

  float acc[3][6];
  #pragma unroll
  for (int r = 0; r < 3; ++r)
    #pragma unroll
    for (int u = 0; u < 6; ++u) acc[r][u] = 0.f;

  int hoA[3], woA[3];
  #pragma unroll
  for (int r = 0; r < 3; ++r) {
    int idx = tid + r*512;
    int hh = (int)((uint)idx / 34u);
    hoA[r] = hh;
    woA[r] = idx - 34*hh;
  }

  int ti = 0, tj = 0;
  for (int tap = 0; tap < 9; ++tap) {
    // 30 uniform dwords (6 u x 5 f16x2) -> scalar loads
    const uint* C = Mh + tap*30;
    uint cu[30];
    #pragma unroll
    for (int j = 0; j < 30; ++j) cu[j] = C[j];

    #pragma unroll
    for (int r = 0; r < 3; ++r) {
      int hh = hoA[r] - ti;
      int wj = woA[r] - tj;
      bool ok = ((uint)hh < 32u) && ((uint)wj < 32u);
      int px = ok ? (hh*32 + wj) : 1024;
      uint2 a = XsA[px];
      uint2 b = XsB[px];
      uint  c = XsC[px];
      h2 v0 = ash2(a.x), v1 = ash2(a.y), v2 = ash2(b.x), v3 = ash2(b.y), v4 = ash2(c);
      #pragma unroll
      for (int u = 0; u < 6; ++u) {
        float d = acc[r][u];
        d = __builtin_amdgcn_fdot2(ash2(cu[u*5+0]), v0, d, false);
        d = __builtin_amdgcn_fdot2(ash2(cu[u*5+1]), v1, d, false);
        d = __builtin_amdgcn_fdot2(ash2(cu[u*5+2]), v2, d, false);
        d = __builtin_amdgcn_fdot2(ash2(cu[u*5+3]), v3, d, false);
        d = __builtin_amdgcn_fdot2(ash2(cu[u*5+4]), v4, d, false);
        acc[r][u] = d;
      }
    }

    if (++tj == 3) { tj = 0; ++ti; }
  }

  // pack 6 bf16 -> 3 dwords per pixel; zeros fill the pad region [1156,1160)
  uint* outp = (uint*)folded + (size_t)blockIdx.x * (NS/2);
  #pragma unroll
  for (int r = 0; r < 3; ++r) {
    int idx = tid + r*512;
    if (idx < SPAD) {
      uint p0 = (uint)f2b(acc[r][0]) | ((uint)f2b(acc[r][1]) << 16);
      uint p1 = (uint)f2b(acc[r][2]) | ((uint)f2b(acc[r][3]) << 16);
      uint p2 = (uint)f2b(acc[r][4]) | ((uint)f2b(acc[r][5]) << 16);
      outp[idx*3+0] = p0;
      outp[idx*3+1] = p1;
      outp[idx*3+2] = p2;
    }
  }
}

// ---- gemm: C[o][n] = sum_c wT[o][c]*folded[b][c][n]; n = s*6+u ----
// 6 waves = 2 M-halves x 3 n-groups; A-fragments preloaded in registers once.
__global__ __launch_bounds__(384) void gemm_kernel(const ushort* __restrict__ wT,
                                                   const ushort* __restrict__ folded,
                                                   float* __restrict__ out) {
  __shared__ __align__(16) char smem[128*52*4];   // 26,624 B (ldsB and ldsC alias)
  ushort* ldsB = (ushort*)smem;                   // [48][136] swizzled
  float*  ldsC = (float*)smem;                    // [128][52]

  int tid  = threadIdx.x;
  int b    = blockIdx.y;
  int tile = blockIdx.x;
  int n0   = tile * NT;

  int wave = tid >> 6, lane = tid & 63;
  int l15 = lane & 15, lhi = lane >> 4;
  int ng = wave % 3;                      // n-group: cols ng*16..+15
  int mh = wave / 3;                      // M-half: rows mh*64..+63
  int nl = ng*16 + l15;                   // 0..47
  int sw = ((nl >> 3) & 7) << 4;

  // preload A fragments (rows mh*64 + mf*16 + l15), issued before stage barrier
  bf16x8 af[4][4];
  {
    const ushort* arow = wT + (mh*64 + l15)*128 + lhi*8;
    #pragma unroll
    for (int mf = 0; mf < 4; ++mf)
      #pragma unroll
      for (int k0 = 0; k0 < 4; ++k0)
        af[mf][k0] = *(const bf16x8*)(arow + mf*16*128 + k0*32);
  }

  // stage B panel [48 n][128 k], transpose + XOR swizzle
  #pragma unroll
  for (int p = 0; p < 2; ++p) {
    int chunk = tid + p*384;              // 0..767 ; c = chunk/6, nc = (chunk%6)*8
    int c  = chunk / 6;
    int nc = (chunk - 6*c) * 8;
    const ushort* src = folded + ((size_t)(b*CIN + c)*NS + n0 + nc);
    uint4 v = *(const uint4*)src;
    ushort e[8];
    e[0]=(ushort)(v.x & 0xffffu); e[1]=(ushort)(v.x >> 16);
    e[2]=(ushort)(v.y & 0xffffu); e[3]=(ushort)(v.y >> 16);
    e[4]=(ushort)(v.z & 0xffffu); e[5]=(ushort)(v.z >> 16);
    e[6]=(ushort)(v.w & 0xffffu); e[7]=(ushort)(v.w >> 16);
    #pragma unroll
    for (int j = 0; j < 8; ++j) {
      int nj  = nc + j;
      int ksw = c ^ (((nj >> 3) & 7) << 4);
      ldsB[nj*136 + ksw] = e[j];
    }
  }
  __syncthreads();

  f32x4 acc[4];
  #pragma unroll
  for (int i = 0; i < 4; ++i) acc[i] = (f32x4){0.f,0.f,0.f,0.f};

  #pragma unroll
  for (int k0 = 0; k0 < 4; ++k0) {
    int kk = k0*32 + lhi*8;
    bf16x8 bfrag = *(const bf16x8*)&ldsB[nl*136 + (kk ^ sw)];
    #pragma unroll
    for (int mf = 0; mf < 4; ++mf)
      acc[mf] = __builtin_amdgcn_mfma_f32_16x16x32_bf16(af[mf][k0], bfrag, acc[mf], 0, 0, 0);
  }

  __syncthreads();   // done reading ldsB
  #pragma unroll
  for (int mf = 0; mf < 4; ++mf)
    #pragma unroll
    for (int r = 0; r < 4; ++r) {
      int o = mh*64 + mf*16 + lhi*4 + r;
      ldsC[o*52 + nl] = acc[mf][r];       // 2-way bank alias only
    }
  __syncthreads();

  // write: one (o, s) pixel per thread-iter -> 9 contiguous f32 (36 B)
  int s0 = tile * 8;
  const int umap[9] = {0,1,2,1,3,4,2,4,5};
  #pragma unroll
  for (int r = 0; r < 3; ++r) {
    int pair = tid + r*384;
    if (pair < 1024) {
      int o  = pair >> 3;
      int sl = pair & 7;
      int s  = s0 + sl;
      if (s < SSP) {
        float v[6];
        #pragma unroll
        for (int u = 0; u < 6; ++u) v[u] = ldsC[o*52 + sl*6 + u];
        size_t base = ((size_t)(b*COUT + o)*SSP + s)*9;
        #pragma unroll
        for (int t = 0; t < 9; ++t) out[base + t] = v[umap[t]];
      }
    }
  }
}

extern "C" void kernel_launch(void* const* d_in, const int* in_sizes, int n_in,
                              void* d_out, int out_size, void* d_ws, size_t ws_size,
                              hipStream_t stream) {
  const float* x = (const float*)d_in[0];
  const float* g = (const float*)d_in[1];
  float* out = (float*)d_out;

  uint*   Mh     = (uint*)d_ws;                           // 270 dwords
  ushort* wT     = (ushort*)((char*)d_ws + 4096);         // 128*128 bf16 = 32 KB
  ushort* folded = (ushort*)((char*)d_ws + 4096 + 32768); // 8*128*6960 bf16 = 14.25 MB

  prep_kernel<<<65, 256, 0, stream>>>(g, Mh, wT);
  fold_kernel<<<NB*CIN, 512, 0, stream>>>(x, Mh, folded);
  gemm_kernel<<<dim3(NS/NT, NB), 384, 0, stream>>>(wT, folded, out);
}